// Round 9
// baseline (180.248 us; speedup 1.0000x reference)
//
#include <hip/hip_runtime.h>
#include <hip/hip_bf16.h>
#include <math.h>

typedef __bf16 bf16;
typedef __bf16 bf16x8 __attribute__((ext_vector_type(8)));
typedef __bf16 bf16x4 __attribute__((ext_vector_type(4)));
typedef float  f32x4  __attribute__((ext_vector_type(4)));
typedef float  f32x16 __attribute__((ext_vector_type(16)));

#define MFMA(a, b, c)   __builtin_amdgcn_mfma_f32_16x16x32_bf16((a), (b), (c), 0, 0, 0)
#define MFMA32(a, b, c) __builtin_amdgcn_mfma_f32_32x32x16_bf16((a), (b), (c), 0, 0, 0)
#define LOG2E 1.4426950408889634f

union U8 { unsigned u[4]; bf16x8 v; };

// ---------------------------------------------------------------------------
// Kernel 0: precast w_qkv^T -> wqT (bf16 [576][192]) and w_proj^T -> wpT.
// ---------------------------------------------------------------------------
__global__ void precast_kernel(const float* __restrict__ w_qkv,
                               const float* __restrict__ w_proj,
                               bf16* __restrict__ wqT, bf16* __restrict__ wpT) {
  int idx = blockIdx.x * 256 + threadIdx.x;
  if (idx < 576 * 192) {
    int c = idx / 192, k = idx % 192;
    wqT[idx] = (bf16)w_qkv[k * 576 + c];
  } else {
    int i2 = idx - 576 * 192;
    if (i2 < 192 * 192) {
      int c = i2 / 192, k = i2 % 192;
      wpT[i2] = (bf16)w_proj[k * 192 + c];
    }
  }
}

// ---------------------------------------------------------------------------
// Kernel A: relative-position-bias MLP (961 rows, 2->12->12->12->6).
// ---------------------------------------------------------------------------
__global__ void pos_mlp_kernel(
    const float* __restrict__ pw0, const float* __restrict__ pb0,
    const float* __restrict__ g1,  const float* __restrict__ be1,
    const float* __restrict__ w1,  const float* __restrict__ b1,
    const float* __restrict__ g2,  const float* __restrict__ be2,
    const float* __restrict__ w2,  const float* __restrict__ b2,
    const float* __restrict__ g3,  const float* __restrict__ be3,
    const float* __restrict__ w3,  const float* __restrict__ b3,
    float* __restrict__ pos_out) {
  int i = blockIdx.x * blockDim.x + threadIdx.x;
  if (i >= 961) return;
  float bh = (float)(i / 31) - 15.0f;
  float bw = (float)(i % 31) - 15.0f;
  float xv[12];
#pragma unroll
  for (int j = 0; j < 12; j++) xv[j] = bh * pw0[j] + bw * pw0[12 + j] + pb0[j];
  const float* G[3]  = {g1, g2, g3};
  const float* BE[3] = {be1, be2, be3};
  const float* W[3]  = {w1, w2, w3};
  const float* BB[3] = {b1, b2, b3};
#pragma unroll
  for (int s = 0; s < 3; s++) {
    float m = 0.f;
#pragma unroll
    for (int j = 0; j < 12; j++) m += xv[j];
    m *= (1.0f / 12.0f);
    float v = 0.f;
#pragma unroll
    for (int j = 0; j < 12; j++) { float d = xv[j] - m; v += d * d; }
    v *= (1.0f / 12.0f);
    float inv = 1.0f / sqrtf(v + 1e-5f);
    float y[12];
#pragma unroll
    for (int j = 0; j < 12; j++) {
      float t = (xv[j] - m) * inv * G[s][j] + BE[s][j];
      y[j] = t > 0.f ? t : 0.f;
    }
    int oc = (s == 2) ? 6 : 12;
    float on[12];
    for (int c = 0; c < oc; c++) {
      float acc = BB[s][c];
#pragma unroll
      for (int j = 0; j < 12; j++) acc += y[j] * W[s][j * oc + c];
      on[c] = acc;
    }
    for (int c = 0; c < 12; c++) xv[c] = (c < oc) ? on[c] : 0.f;
  }
  for (int hh = 0; hh < 6; hh++) pos_out[hh * 961 + i] = xv[hh];
}

// ---------------------------------------------------------------------------
// Kernel A2: build the lane-permuted pos table for the 32x32 attn layout.
// pos32g[h][rd][L][j] = pos[h][rd*31 + (L&15) - ((j&3)+8*(j>>2)+4*(L>>5)) + 15]
//                       * LOG2E   (bf16)
// ---------------------------------------------------------------------------
__global__ void pos32_build_kernel(const float* __restrict__ posg,
                                   bf16* __restrict__ pos32g) {
  int rd = blockIdx.x, h = blockIdx.y;
  int t = threadIdx.x;
  for (int e = t; e < 512; e += 256) {
    int L = e >> 3, j = e & 7;
    int qh = L & 15;
    int hi = L >> 5;
    int idx = rd * 31 + qh - ((j & 3) + 8 * (j >> 2) + 4 * hi) + 15;
    pos32g[((h * 31 + rd) * 64 + L) * 8 + j] = (bf16)(posg[h * 961 + idx] * LOG2E);
  }
}

// ---------------------------------------------------------------------------
// Kernel B: QKV GEMM.  grid 512, 4 waves x 32 rows (BM=128, rt=2).
// W^T staged in LDS one mat at a time.  Q pre-scaled by scale*log2e.
// Q,K swapped-MFMA -> [b][h][n][d]; V normal -> vT[b][h][d][n].
// ---------------------------------------------------------------------------
#define SMEM_G (192 * 200 * 2)

__global__ __launch_bounds__(256) void qkv_gemm_kernel(
    const float* __restrict__ x, const bf16* __restrict__ wqT,
    const float* __restrict__ b_qkv, bf16* __restrict__ qw,
    bf16* __restrict__ kw, bf16* __restrict__ vwT) {
  extern __shared__ char smem[];
  bf16* wt = (bf16*)smem;   // [192 c][200 k]
  const int tid = threadIdx.x;
  const int lane = tid & 63, w = tid >> 6;
  const int cI = lane & 15, gI = lane >> 4;
  const int row0 = blockIdx.x * 128 + w * 32;
  const int b = blockIdx.x >> 1;
  const float QSCALE = 0.17677669529663687f * LOG2E;

  bf16x8 afr[2][6];
#pragma unroll
  for (int rt = 0; rt < 2; rt++) {
#pragma unroll
    for (int kk = 0; kk < 6; kk++) {
      const float* p = x + (size_t)(row0 + rt * 16 + cI) * 192 + kk * 32 + gI * 8;
      float4 f0 = *(const float4*)p;
      float4 f1 = *(const float4*)(p + 4);
      bf16x8 a;
      a[0] = (bf16)f0.x; a[1] = (bf16)f0.y; a[2] = (bf16)f0.z; a[3] = (bf16)f0.w;
      a[4] = (bf16)f1.x; a[5] = (bf16)f1.y; a[6] = (bf16)f1.z; a[7] = (bf16)f1.w;
      afr[rt][kk] = a;
    }
  }

#pragma unroll
  for (int mat = 0; mat < 3; mat++) {
    __syncthreads();
#pragma unroll
    for (int it = 0; it < 18; it++) {
      int idx = it * 256 + tid;
      int c = idx / 24, ch = idx % 24;
      bf16x8 v8 = *(const bf16x8*)(wqT + (size_t)(mat * 192 + c) * 192 + ch * 8);
      *(bf16x8*)(wt + c * 200 + ch * 8) = v8;
    }
    __syncthreads();
#pragma unroll
    for (int ct = 0; ct < 12; ct++) {
      bf16x8 wfr[6];
#pragma unroll
      for (int kk = 0; kk < 6; kk++)
        wfr[kk] = *(const bf16x8*)(wt + (ct * 16 + cI) * 200 + kk * 32 + gI * 8);
      if (mat < 2) {
        f32x4 bv4 = *(const f32x4*)(b_qkv + mat * 192 + ct * 16 + gI * 4);
        bf16* dst = (mat == 0) ? qw : kw;
#pragma unroll
        for (int rt = 0; rt < 2; rt++) {
          f32x4 acc = {0.f, 0.f, 0.f, 0.f};
#pragma unroll
          for (int kk = 0; kk < 6; kk++) acc = MFMA(wfr[kk], afr[rt][kk], acc);
          int n = (row0 + rt * 16 + cI) & 255;
          int c0 = ct * 16 + gI * 4;
          int h = c0 >> 5, d0 = c0 & 31;
          bf16x4 o4;
          if (mat == 0) {
#pragma unroll
            for (int r = 0; r < 4; r++) o4[r] = (bf16)((acc[r] + bv4[r]) * QSCALE);
          } else {
#pragma unroll
            for (int r = 0; r < 4; r++) o4[r] = (bf16)(acc[r] + bv4[r]);
          }
          *(bf16x4*)(dst + ((size_t)(b * 6 + h) * 256 + n) * 32 + d0) = o4;
        }
      } else {
        float bv = b_qkv[384 + ct * 16 + cI];
        int c = ct * 16 + cI, h = c >> 5, d = c & 31;
#pragma unroll
        for (int rt = 0; rt < 2; rt++) {
          f32x4 acc = {0.f, 0.f, 0.f, 0.f};
#pragma unroll
          for (int kk = 0; kk < 6; kk++) acc = MFMA(afr[rt][kk], wfr[kk], acc);
          int n0 = ((row0 + rt * 16) & 255) + gI * 4;
          bf16x4 o4;
#pragma unroll
          for (int r = 0; r < 4; r++) o4[r] = (bf16)(acc[r] + bv);
          *(bf16x4*)(vwT + ((size_t)(b * 6 + h) * 32 + d) * 256 + n0) = o4;
        }
      }
    }
  }
}

// ---------------------------------------------------------------------------
// Kernel C: flash attention, 32x32 MFMA, fully in-register P.
// grid 3072 (b, h, half), 4 waves x 32 q rows.  ZERO LDS, no syncthreads.
// S = MFMA32(K_frag, Q_frag): row=m, col=q=lane&31.  P feeds PV with NO
// redistribution: V's B-frag k-order is sigma-permuted to match P's natural
// C-layout (slot (hi,j) <-> m = 4hi + (j&3) + 8*(j>>2)); the contraction is
// invariant under a shared k-permutation.  l via ones-MFMA (perm-invariant).
// Defer-max THR=8.
// ---------------------------------------------------------------------------
__global__ __launch_bounds__(256, 4) void attn_kernel(
    const bf16* __restrict__ qw, const bf16* __restrict__ kw,
    const bf16* __restrict__ vwT, const float* __restrict__ mask,
    const bf16* __restrict__ pos32g, bf16* __restrict__ ctx) {
  const int tid = threadIdx.x;
  const int bid = blockIdx.x;
  const int s_ = bid & 63, j_ = bid >> 6;          // mask slice; XCD = bid%8 = s_%8
  const int g_ = j_ & 3, t2 = j_ >> 2;
  const int h = t2 % 6, half = t2 / 6;
  const int b = g_ * 64 + s_;

  const bf16* qb = qw  + (size_t)(b * 6 + h) * 8192;
  const bf16* kb = kw  + (size_t)(b * 6 + h) * 8192;
  const bf16* vb = vwT + (size_t)(b * 6 + h) * 8192;
  const bf16* pg = pos32g + (size_t)h * (31 * 512);
  const float* maskb = mask + (size_t)s_ * 65536;

  const int lane = tid & 63, w = tid >> 6;
  const int q5 = lane & 31, hi = lane >> 5;
  const int q_abs = half * 128 + w * 32 + q5;
  const int rn = q_abs >> 4;

  // Q B-frag (col=q=lane&31, k=d): held for the whole kernel
  bf16x8 qf0 = *(const bf16x8*)(qb + q_abs * 32 + hi * 8);
  bf16x8 qf1 = *(const bf16x8*)(qb + q_abs * 32 + 16 + hi * 8);

  bf16x8 ones8;
#pragma unroll
  for (int j = 0; j < 8; j++) ones8[j] = (bf16)1.0f;

  f32x16 o, ol;
#pragma unroll
  for (int r = 0; r < 16; r++) { o[r] = 0.f; ol[r] = 0.f; }
  float mr = -3.0e38f;

  for (int mt = 0; mt < 8; mt++) {
    const int m0 = mt * 32;
    // K A-frag (row=m=lane&31, k=d)
    bf16x8 kf0 = *(const bf16x8*)(kb + (m0 + q5) * 32 + hi * 8);
    bf16x8 kf1 = *(const bf16x8*)(kb + (m0 + q5) * 32 + 16 + hi * 8);
    // V B-frag, sigma-permuted k-order: slot (hi,j) = m0(+16) + 4hi + {0..3,8..11}
    const bf16* vrow = vb + q5 * 256 + m0 + 4 * hi;
    bf16x4 v00 = *(const bf16x4*)(vrow);
    bf16x4 v01 = *(const bf16x4*)(vrow + 8);
    bf16x4 v10 = *(const bf16x4*)(vrow + 16);
    bf16x4 v11 = *(const bf16x4*)(vrow + 24);
    bf16x8 vf0, vf1;
#pragma unroll
    for (int j2 = 0; j2 < 4; j2++) {
      vf0[j2] = v00[j2]; vf0[4 + j2] = v01[j2];
      vf1[j2] = v10[j2]; vf1[4 + j2] = v11[j2];
    }
    // bias loads (independent of MFMA)
    const int rd0 = rn - 2 * mt + 15;
    bf16x8 plo = *(const bf16x8*)(pg + ((rd0)*64 + lane) * 8);
    bf16x8 phi = *(const bf16x8*)(pg + ((rd0 - 1) * 64 + lane) * 8);
    const float* mrow = maskb + (size_t)q_abs * 256 + m0 + 4 * hi;
    f32x4 mv0 = *(const f32x4*)(mrow);
    f32x4 mv1 = *(const f32x4*)(mrow + 8);
    f32x4 mv2 = *(const f32x4*)(mrow + 16);
    f32x4 mv3 = *(const f32x4*)(mrow + 24);

    f32x16 sa;
#pragma unroll
    for (int r = 0; r < 16; r++) sa[r] = 0.f;
    __builtin_amdgcn_s_setprio(1);
    sa = MFMA32(kf0, qf0, sa);
    sa = MFMA32(kf1, qf1, sa);
    __builtin_amdgcn_s_setprio(0);

    // add bias: row m = (r&3)+8*(r>>2)+4*hi, col q = lane&31
#pragma unroll
    for (int r = 0; r < 8; r++) {
      float mv = (r < 4) ? mv0[r & 3] : mv1[r & 3];
      sa[r] = fmaf(mv, LOG2E, sa[r] + (float)plo[r]);
    }
#pragma unroll
    for (int r = 8; r < 16; r++) {
      float mv = (r < 12) ? mv2[r & 3] : mv3[r & 3];
      sa[r] = fmaf(mv, LOG2E, sa[r] + (float)phi[r - 8]);
    }

    // column (q) max: 16 in-lane + 1 cross-half shuffle
    float t = sa[0];
#pragma unroll
    for (int r = 1; r < 16; r++) t = fmaxf(t, sa[r]);
    t = fmaxf(t, __shfl_xor(t, 32));

    if (!__all(t - mr <= 8.0f)) {          // defer-max: rare after tile 0
      float mn = fmaxf(mr, t);
      float fsc = exp2f(mr - mn);
      mr = mn;
#pragma unroll
      for (int r = 0; r < 16; r++) {
        float f = __shfl(fsc, (r & 3) + 8 * (r >> 2) + 4 * hi);
        o[r] *= f; ol[r] *= f;
      }
    }

    // P = 2^(sa - mr); A-frags are the raw cvt_pk outputs in sequence:
    // A1 slot (hi,j) holds m = 4hi + (j&3) + 8*(j>>2)  (matches vf0's sigma)
#pragma unroll
    for (int r = 0; r < 16; r++) sa[r] = exp2f(sa[r] - mr);
    unsigned a0, a1, b0, b1, c0, c1, d0, d1;
    asm("v_cvt_pk_bf16_f32 %0, %1, %2" : "=v"(a0) : "v"(sa[0]),  "v"(sa[1]));
    asm("v_cvt_pk_bf16_f32 %0, %1, %2" : "=v"(a1) : "v"(sa[2]),  "v"(sa[3]));
    asm("v_cvt_pk_bf16_f32 %0, %1, %2" : "=v"(b0) : "v"(sa[4]),  "v"(sa[5]));
    asm("v_cvt_pk_bf16_f32 %0, %1, %2" : "=v"(b1) : "v"(sa[6]),  "v"(sa[7]));
    asm("v_cvt_pk_bf16_f32 %0, %1, %2" : "=v"(c0) : "v"(sa[8]),  "v"(sa[9]));
    asm("v_cvt_pk_bf16_f32 %0, %1, %2" : "=v"(c1) : "v"(sa[10]), "v"(sa[11]));
    asm("v_cvt_pk_bf16_f32 %0, %1, %2" : "=v"(d0) : "v"(sa[12]), "v"(sa[13]));
    asm("v_cvt_pk_bf16_f32 %0, %1, %2" : "=v"(d1) : "v"(sa[14]), "v"(sa[15]));
    U8 A1, A2;
    A1.u[0] = a0; A1.u[1] = a1; A1.u[2] = b0; A1.u[3] = b1;   // m-chunk 0..15 (sigma)
    A2.u[0] = c0; A2.u[1] = c1; A2.u[2] = d0; A2.u[3] = d1;   // m-chunk 16..31 (sigma)

    __builtin_amdgcn_s_setprio(1);
    o  = MFMA32(A1.v, vf0, o);
    o  = MFMA32(A2.v, vf1, o);
    ol = MFMA32(A1.v, ones8, ol);
    ol = MFMA32(A2.v, ones8, ol);
    __builtin_amdgcn_s_setprio(0);
  }

  // epilogue: o and ol layout-matched (row q, col d) -> plain divide
#pragma unroll
  for (int r = 0; r < 16; r++) {
    int qa = half * 128 + w * 32 + (r & 3) + 8 * (r >> 2) + 4 * hi;
    float val = o[r] / ol[r];
    ctx[((size_t)(b << 8) + qa) * 192 + h * 32 + q5] = (bf16)val;
  }
}

// ---------------------------------------------------------------------------
// Kernel D: out = ctx @ w_proj + b_proj.  grid 512, rt=2, W^T staged in LDS,
// swapped orientation -> float4 stores.
// ---------------------------------------------------------------------------
#define SMEM_C (192 * 200 * 2)

__global__ __launch_bounds__(256) void proj_kernel(
    const bf16* __restrict__ ctx, const bf16* __restrict__ wpT,
    const float* __restrict__ b_proj, float* __restrict__ out) {
  extern __shared__ char smem[];
  bf16* wt = (bf16*)smem;   // [192 c][200 k]
  const int tid = threadIdx.x;
#pragma unroll
  for (int it = 0; it < 18; it++) {
    int idx = it * 256 + tid;
    int c = idx / 24, ch = idx % 24;
    bf16x8 v8 = *(const bf16x8*)(wpT + (size_t)c * 192 + ch * 8);
    *(bf16x8*)(wt + c * 200 + ch * 8) = v8;
  }
  __syncthreads();
  const int lane = tid & 63, w = tid >> 6;
  const int cI = lane & 15, gI = lane >> 4;
  const int row0 = blockIdx.x * 128 + w * 32;
  bf16x8 afr[2][6];
#pragma unroll
  for (int rt = 0; rt < 2; rt++) {
#pragma unroll
    for (int kk = 0; kk < 6; kk++)
      afr[rt][kk] = *(const bf16x8*)(ctx + (size_t)(row0 + rt * 16 + cI) * 192 +
                                     kk * 32 + gI * 8);
  }
#pragma unroll
  for (int ct = 0; ct < 12; ct++) {
    bf16x8 wfr[6];
#pragma unroll
    for (int kk = 0; kk < 6; kk++)
      wfr[kk] = *(const bf16x8*)(wt + (ct * 16 + cI) * 200 + kk * 32 + gI * 8);
    f32x4 bv4 = *(const f32x4*)(b_proj + ct * 16 + gI * 4);
#pragma unroll
    for (int rt = 0; rt < 2; rt++) {
      f32x4 acc = {0.f, 0.f, 0.f, 0.f};
#pragma unroll
      for (int kk = 0; kk < 6; kk++) acc = MFMA(wfr[kk], afr[rt][kk], acc);
      f32x4 res;
#pragma unroll
      for (int r = 0; r < 4; r++) res[r] = acc[r] + bv4[r];
      *(f32x4*)(out + (size_t)(row0 + rt * 16 + cI) * 192 + ct * 16 + gI * 4) = res;
    }
  }
}

// ---------------------------------------------------------------------------
extern "C" void kernel_launch(void* const* d_in, const int* in_sizes, int n_in,
                              void* d_out, int out_size, void* d_ws, size_t ws_size,
                              hipStream_t stream) {
  (void)in_sizes; (void)n_in; (void)out_size; (void)ws_size;
  const float* x      = (const float*)d_in[0];
  const float* mask   = (const float*)d_in[1];
  const float* w_qkv  = (const float*)d_in[2];
  const float* b_qkv  = (const float*)d_in[3];
  const float* w_proj = (const float*)d_in[4];
  const float* b_proj = (const float*)d_in[5];
  const float* pw0    = (const float*)d_in[6];
  const float* pb0    = (const float*)d_in[7];
  const float* g1     = (const float*)d_in[8];
  const float* be1    = (const float*)d_in[9];
  const float* w1     = (const float*)d_in[10];
  const float* b1     = (const float*)d_in[11];
  const float* g2     = (const float*)d_in[12];
  const float* be2    = (const float*)d_in[13];
  const float* w2     = (const float*)d_in[14];
  const float* b2     = (const float*)d_in[15];
  const float* g3     = (const float*)d_in[16];
  const float* be3    = (const float*)d_in[17];
  const float* w3     = (const float*)d_in[18];
  const float* b3     = (const float*)d_in[19];

  // ws layout (peak ~96.5 MB):
  //   posw   @ 0         (24576)
  //   wqT    @ 24576     (221184)   bf16 [576][192]
  //   wpT    @ 245760    (73728)    bf16 [192][192]
  //   pos32g @ 319488    (190464)   bf16 [6][31][64][8]  (pre-permuted, *log2e)
  //   qw     @ 516096    (25165824) bf16 [b][h][n][32]   (pre-scaled s*log2e)
  //   kw     @ 25681920  (25165824)
  //   vwT    @ 50847744  (25165824) bf16 [b][h][32][n]
  //   ctx    @ 76013568  (25165824)
  char* ws = (char*)d_ws;
  float* posw   = (float*)ws;
  bf16*  wqT    = (bf16*)(ws + 24576);
  bf16*  wpT    = (bf16*)(ws + 245760);
  bf16*  pos32g = (bf16*)(ws + 319488);
  bf16*  qw     = (bf16*)(ws + 516096);
  bf16*  kw     = (bf16*)(ws + 25681920);
  bf16*  vwT    = (bf16*)(ws + 50847744);
  bf16*  ctx    = (bf16*)(ws + 76013568);
  float* outp   = (float*)d_out;

  hipFuncSetAttribute((const void*)qkv_gemm_kernel,
                      hipFuncAttributeMaxDynamicSharedMemorySize, SMEM_G);
  hipFuncSetAttribute((const void*)proj_kernel,
                      hipFuncAttributeMaxDynamicSharedMemorySize, SMEM_C);

  precast_kernel<<<dim3(576), dim3(256), 0, stream>>>(w_qkv, w_proj, wqT, wpT);
  pos_mlp_kernel<<<dim3(4), dim3(256), 0, stream>>>(
      pw0, pb0, g1, be1, w1, b1, g2, be2, w2, b2, g3, be3, w3, b3, posw);
  pos32_build_kernel<<<dim3(31, 6), dim3(256), 0, stream>>>(posw, pos32g);
  qkv_gemm_kernel<<<dim3(512), dim3(256), SMEM_G, stream>>>(
      x, wqT, b_qkv, qw, kw, vwT);
  attn_kernel<<<dim3(3072), dim3(256), 0, stream>>>(
      qw, kw, vwT, mask, pos32g, ctx);
  proj_kernel<<<dim3(512), dim3(256), SMEM_C, stream>>>(
      ctx, wpT, b_proj, outp);
}

// Round 10
// 138.941 us; speedup vs baseline: 1.2973x; 1.2973x over previous
//
#include <hip/hip_runtime.h>
#include <hip/hip_bf16.h>
#include <math.h>

typedef __bf16 bf16;
typedef __bf16 bf16x8 __attribute__((ext_vector_type(8)));
typedef __bf16 bf16x4 __attribute__((ext_vector_type(4)));
typedef float  f32x4  __attribute__((ext_vector_type(4)));
typedef float  f32x16 __attribute__((ext_vector_type(16)));
typedef _Float16 f16x8 __attribute__((ext_vector_type(8)));

#define MFMA(a, b, c)   __builtin_amdgcn_mfma_f32_16x16x32_bf16((a), (b), (c), 0, 0, 0)
#define MFMA32(a, b, c) __builtin_amdgcn_mfma_f32_32x32x16_bf16((a), (b), (c), 0, 0, 0)
#define LOG2E 1.4426950408889634f

union U8 { unsigned u[4]; bf16x8 v; };

// ---------------------------------------------------------------------------
// Kernel 0: precast w_qkv^T -> wqT (bf16 [576][192]) and w_proj^T -> wpT.
// ---------------------------------------------------------------------------
__global__ void precast_kernel(const float* __restrict__ w_qkv,
                               const float* __restrict__ w_proj,
                               bf16* __restrict__ wqT, bf16* __restrict__ wpT) {
  int idx = blockIdx.x * 256 + threadIdx.x;
  if (idx < 576 * 192) {
    int c = idx / 192, k = idx % 192;
    wqT[idx] = (bf16)w_qkv[k * 576 + c];
  } else {
    int i2 = idx - 576 * 192;
    if (i2 < 192 * 192) {
      int c = i2 / 192, k = i2 % 192;
      wpT[i2] = (bf16)w_proj[k * 192 + c];
    }
  }
}

// ---------------------------------------------------------------------------
// Kernel A: relative-position-bias MLP (961 rows, 2->12->12->12->6).
// ---------------------------------------------------------------------------
__global__ void pos_mlp_kernel(
    const float* __restrict__ pw0, const float* __restrict__ pb0,
    const float* __restrict__ g1,  const float* __restrict__ be1,
    const float* __restrict__ w1,  const float* __restrict__ b1,
    const float* __restrict__ g2,  const float* __restrict__ be2,
    const float* __restrict__ w2,  const float* __restrict__ b2,
    const float* __restrict__ g3,  const float* __restrict__ be3,
    const float* __restrict__ w3,  const float* __restrict__ b3,
    float* __restrict__ pos_out) {
  int i = blockIdx.x * blockDim.x + threadIdx.x;
  if (i >= 961) return;
  float bh = (float)(i / 31) - 15.0f;
  float bw = (float)(i % 31) - 15.0f;
  float xv[12];
#pragma unroll
  for (int j = 0; j < 12; j++) xv[j] = bh * pw0[j] + bw * pw0[12 + j] + pb0[j];
  const float* G[3]  = {g1, g2, g3};
  const float* BE[3] = {be1, be2, be3};
  const float* W[3]  = {w1, w2, w3};
  const float* BB[3] = {b1, b2, b3};
#pragma unroll
  for (int s = 0; s < 3; s++) {
    float m = 0.f;
#pragma unroll
    for (int j = 0; j < 12; j++) m += xv[j];
    m *= (1.0f / 12.0f);
    float v = 0.f;
#pragma unroll
    for (int j = 0; j < 12; j++) { float d = xv[j] - m; v += d * d; }
    v *= (1.0f / 12.0f);
    float inv = 1.0f / sqrtf(v + 1e-5f);
    float y[12];
#pragma unroll
    for (int j = 0; j < 12; j++) {
      float t = (xv[j] - m) * inv * G[s][j] + BE[s][j];
      y[j] = t > 0.f ? t : 0.f;
    }
    int oc = (s == 2) ? 6 : 12;
    float on[12];
    for (int c = 0; c < oc; c++) {
      float acc = BB[s][c];
#pragma unroll
      for (int j = 0; j < 12; j++) acc += y[j] * W[s][j * oc + c];
      on[c] = acc;
    }
    for (int c = 0; c < 12; c++) xv[c] = (c < oc) ? on[c] : 0.f;
  }
  for (int hh = 0; hh < 6; hh++) pos_out[hh * 961 + i] = xv[hh];
}

// ---------------------------------------------------------------------------
// Kernel A2: lane-permuted pos table for the 32x32 attn layout (as R9).
// ---------------------------------------------------------------------------
__global__ void pos32_build_kernel(const float* __restrict__ posg,
                                   bf16* __restrict__ pos32g) {
  int rd = blockIdx.x, h = blockIdx.y;
  int t = threadIdx.x;
  for (int e = t; e < 512; e += 256) {
    int L = e >> 3, j = e & 7;
    int qh = L & 15;
    int hi = L >> 5;
    int idx = rd * 31 + qh - ((j & 3) + 8 * (j >> 2) + 4 * hi) + 15;
    pos32g[((h * 31 + rd) * 64 + L) * 8 + j] = (bf16)(posg[h * 961 + idx] * LOG2E);
  }
}

// ---------------------------------------------------------------------------
// Kernel A3: lane-permuted f16 mask table.
// maskp[s][qt][mt][L][j] = mask[s][qt*32+(L&31)]
//                              [mt*32 + 16*(j>>3) + 8*((j>>2)&1) + 4*(L>>5) + (j&3)]
//                          * LOG2E
// Attn reads lane L's 16 values as 32 contiguous bytes -> fully coalesced.
// ---------------------------------------------------------------------------
__global__ __launch_bounds__(256) void maskprep_kernel(
    const float* __restrict__ mask, _Float16* __restrict__ maskp) {
  size_t e = ((size_t)blockIdx.x * 256 + threadIdx.x) * 2;
  int j  = (int)(e & 15);
  int L  = (int)((e >> 4) & 63);
  int mt = (int)((e >> 10) & 7);
  int qt = (int)((e >> 13) & 7);
  int s  = (int)(e >> 16);
  int q  = qt * 32 + (L & 31);
  int m  = mt * 32 + 16 * (j >> 3) + 8 * ((j >> 2) & 1) + 4 * (L >> 5) + (j & 3);
  const float* src = mask + ((size_t)s * 256 + q) * 256 + m;
  maskp[e]     = (_Float16)(src[0] * LOG2E);
  maskp[e + 1] = (_Float16)(src[1] * LOG2E);
}

// ---------------------------------------------------------------------------
// Kernel B: QKV GEMM (unchanged from R9).  grid 512, BM=128, rt=2.
// ---------------------------------------------------------------------------
#define SMEM_G (192 * 200 * 2)

__global__ __launch_bounds__(256) void qkv_gemm_kernel(
    const float* __restrict__ x, const bf16* __restrict__ wqT,
    const float* __restrict__ b_qkv, bf16* __restrict__ qw,
    bf16* __restrict__ kw, bf16* __restrict__ vwT) {
  extern __shared__ char smem[];
  bf16* wt = (bf16*)smem;   // [192 c][200 k]
  const int tid = threadIdx.x;
  const int lane = tid & 63, w = tid >> 6;
  const int cI = lane & 15, gI = lane >> 4;
  const int row0 = blockIdx.x * 128 + w * 32;
  const int b = blockIdx.x >> 1;
  const float QSCALE = 0.17677669529663687f * LOG2E;

  bf16x8 afr[2][6];
#pragma unroll
  for (int rt = 0; rt < 2; rt++) {
#pragma unroll
    for (int kk = 0; kk < 6; kk++) {
      const float* p = x + (size_t)(row0 + rt * 16 + cI) * 192 + kk * 32 + gI * 8;
      float4 f0 = *(const float4*)p;
      float4 f1 = *(const float4*)(p + 4);
      bf16x8 a;
      a[0] = (bf16)f0.x; a[1] = (bf16)f0.y; a[2] = (bf16)f0.z; a[3] = (bf16)f0.w;
      a[4] = (bf16)f1.x; a[5] = (bf16)f1.y; a[6] = (bf16)f1.z; a[7] = (bf16)f1.w;
      afr[rt][kk] = a;
    }
  }

#pragma unroll
  for (int mat = 0; mat < 3; mat++) {
    __syncthreads();
#pragma unroll
    for (int it = 0; it < 18; it++) {
      int idx = it * 256 + tid;
      int c = idx / 24, ch = idx % 24;
      bf16x8 v8 = *(const bf16x8*)(wqT + (size_t)(mat * 192 + c) * 192 + ch * 8);
      *(bf16x8*)(wt + c * 200 + ch * 8) = v8;
    }
    __syncthreads();
#pragma unroll
    for (int ct = 0; ct < 12; ct++) {
      bf16x8 wfr[6];
#pragma unroll
      for (int kk = 0; kk < 6; kk++)
        wfr[kk] = *(const bf16x8*)(wt + (ct * 16 + cI) * 200 + kk * 32 + gI * 8);
      if (mat < 2) {
        f32x4 bv4 = *(const f32x4*)(b_qkv + mat * 192 + ct * 16 + gI * 4);
        bf16* dst = (mat == 0) ? qw : kw;
#pragma unroll
        for (int rt = 0; rt < 2; rt++) {
          f32x4 acc = {0.f, 0.f, 0.f, 0.f};
#pragma unroll
          for (int kk = 0; kk < 6; kk++) acc = MFMA(wfr[kk], afr[rt][kk], acc);
          int n = (row0 + rt * 16 + cI) & 255;
          int c0 = ct * 16 + gI * 4;
          int h = c0 >> 5, d0 = c0 & 31;
          bf16x4 o4;
          if (mat == 0) {
#pragma unroll
            for (int r = 0; r < 4; r++) o4[r] = (bf16)((acc[r] + bv4[r]) * QSCALE);
          } else {
#pragma unroll
            for (int r = 0; r < 4; r++) o4[r] = (bf16)(acc[r] + bv4[r]);
          }
          *(bf16x4*)(dst + ((size_t)(b * 6 + h) * 256 + n) * 32 + d0) = o4;
        }
      } else {
        float bv = b_qkv[384 + ct * 16 + cI];
        int c = ct * 16 + cI, h = c >> 5, d = c & 31;
#pragma unroll
        for (int rt = 0; rt < 2; rt++) {
          f32x4 acc = {0.f, 0.f, 0.f, 0.f};
#pragma unroll
          for (int kk = 0; kk < 6; kk++) acc = MFMA(afr[rt][kk], wfr[kk], acc);
          int n0 = ((row0 + rt * 16) & 255) + gI * 4;
          bf16x4 o4;
#pragma unroll
          for (int r = 0; r < 4; r++) o4[r] = (bf16)(acc[r] + bv);
          *(bf16x4*)(vwT + ((size_t)(b * 6 + h) * 32 + d) * 256 + n0) = o4;
        }
      }
    }
  }
}

// ---------------------------------------------------------------------------
// Kernel C: flash attention, 32x32 MFMA, zero LDS.  grid 1536 (b,h),
// 4 waves x 64 q rows = 2 subtiles of 32.  K/V frags shared across subtiles.
// Bias via pre-permuted coalesced f16 maskp + bf16 pos32g.  l = in-lane sum.
// sigma-permuted PV contraction (verified R9).  Defer-max THR=8.
// ---------------------------------------------------------------------------
__global__ __launch_bounds__(256, 4) void attn_kernel(
    const bf16* __restrict__ qw, const bf16* __restrict__ kw,
    const bf16* __restrict__ vwT, const _Float16* __restrict__ maskp,
    const bf16* __restrict__ pos32g, bf16* __restrict__ ctx) {
  const int tid = threadIdx.x;
  const int bid = blockIdx.x;
  const int s_ = bid & 63, j_ = bid >> 6;          // mask slice; XCD = bid%8 = s_%8
  const int g_ = j_ & 3, h = j_ >> 2;
  const int b = g_ * 64 + s_;

  const bf16* qb = qw  + (size_t)(b * 6 + h) * 8192;
  const bf16* kb = kw  + (size_t)(b * 6 + h) * 8192;
  const bf16* vb = vwT + (size_t)(b * 6 + h) * 8192;
  const bf16* pg = pos32g + (size_t)h * (31 * 512);

  const int lane = tid & 63, w = tid >> 6;
  const int q5 = lane & 31, hi = lane >> 5;

  // Q B-frags for both subtiles (held for whole kernel)
  bf16x8 qf[2][2];
#pragma unroll
  for (int sub = 0; sub < 2; sub++) {
    int qa = w * 64 + sub * 32 + q5;
    qf[sub][0] = *(const bf16x8*)(qb + qa * 32 + hi * 8);
    qf[sub][1] = *(const bf16x8*)(qb + qa * 32 + 16 + hi * 8);
  }

  f32x16 o[2];
  float l[2], mr[2];
#pragma unroll
  for (int sub = 0; sub < 2; sub++) {
#pragma unroll
    for (int r = 0; r < 16; r++) o[sub][r] = 0.f;
    l[sub] = 0.f; mr[sub] = -3.0e38f;
  }

  for (int mt = 0; mt < 8; mt++) {
    const int m0 = mt * 32;
    // K A-frag + V B-frag: shared across both q-subtiles
    bf16x8 kf0 = *(const bf16x8*)(kb + (m0 + q5) * 32 + hi * 8);
    bf16x8 kf1 = *(const bf16x8*)(kb + (m0 + q5) * 32 + 16 + hi * 8);
    const bf16* vrow = vb + q5 * 256 + m0 + 4 * hi;
    bf16x4 v00 = *(const bf16x4*)(vrow);
    bf16x4 v01 = *(const bf16x4*)(vrow + 8);
    bf16x4 v10 = *(const bf16x4*)(vrow + 16);
    bf16x4 v11 = *(const bf16x4*)(vrow + 24);
    bf16x8 vf0, vf1;
#pragma unroll
    for (int j2 = 0; j2 < 4; j2++) {
      vf0[j2] = v00[j2]; vf0[4 + j2] = v01[j2];
      vf1[j2] = v10[j2]; vf1[4 + j2] = v11[j2];
    }

#pragma unroll
    for (int sub = 0; sub < 2; sub++) {
      const int qa = w * 64 + sub * 32 + q5;
      const int rn = qa >> 4;
      const int rd0 = rn - 2 * mt + 15;
      bf16x8 plo = *(const bf16x8*)(pg + ((rd0)*64 + lane) * 8);
      bf16x8 phi = *(const bf16x8*)(pg + ((rd0 - 1) * 64 + lane) * 8);
      const _Float16* mrow =
          maskp + ((((size_t)s_ * 8 + (w * 2 + sub)) * 8 + mt) * 64 + lane) * 16;
      f16x8 mk0 = *(const f16x8*)(mrow);
      f16x8 mk1 = *(const f16x8*)(mrow + 8);

      f32x16 sa;
#pragma unroll
      for (int r = 0; r < 16; r++) sa[r] = 0.f;
      __builtin_amdgcn_s_setprio(1);
      sa = MFMA32(kf0, qf[sub][0], sa);
      sa = MFMA32(kf1, qf[sub][1], sa);
      __builtin_amdgcn_s_setprio(0);

#pragma unroll
      for (int r = 0; r < 8; r++)  sa[r] += (float)mk0[r] + (float)plo[r];
#pragma unroll
      for (int r = 8; r < 16; r++) sa[r] += (float)mk1[r - 8] + (float)phi[r - 8];

      // column (q) max: 15 in-lane + 1 cross-half shuffle
      float t = sa[0];
#pragma unroll
      for (int r = 1; r < 16; r++) t = fmaxf(t, sa[r]);
      t = fmaxf(t, __shfl_xor(t, 32));

      if (!__all(t - mr[sub] <= 8.0f)) {     // defer-max: rare after tile 0
        float mn = fmaxf(mr[sub], t);
        float fsc = exp2f(mr[sub] - mn);
        mr[sub] = mn;
        l[sub] *= fsc;
#pragma unroll
        for (int r = 0; r < 16; r++) {
          float f = __shfl(fsc, (r & 3) + 8 * (r >> 2) + 4 * hi);
          o[sub][r] *= f;
        }
      }

      float ls = 0.f;
#pragma unroll
      for (int r = 0; r < 16; r++) {
        float p = exp2f(sa[r] - mr[sub]);
        sa[r] = p;
        ls += p;
      }
      ls += __shfl_xor(ls, 32);
      l[sub] += ls;

      unsigned a0, a1, b0, b1, c0, c1, d0, d1;
      asm("v_cvt_pk_bf16_f32 %0, %1, %2" : "=v"(a0) : "v"(sa[0]),  "v"(sa[1]));
      asm("v_cvt_pk_bf16_f32 %0, %1, %2" : "=v"(a1) : "v"(sa[2]),  "v"(sa[3]));
      asm("v_cvt_pk_bf16_f32 %0, %1, %2" : "=v"(b0) : "v"(sa[4]),  "v"(sa[5]));
      asm("v_cvt_pk_bf16_f32 %0, %1, %2" : "=v"(b1) : "v"(sa[6]),  "v"(sa[7]));
      asm("v_cvt_pk_bf16_f32 %0, %1, %2" : "=v"(c0) : "v"(sa[8]),  "v"(sa[9]));
      asm("v_cvt_pk_bf16_f32 %0, %1, %2" : "=v"(c1) : "v"(sa[10]), "v"(sa[11]));
      asm("v_cvt_pk_bf16_f32 %0, %1, %2" : "=v"(d0) : "v"(sa[12]), "v"(sa[13]));
      asm("v_cvt_pk_bf16_f32 %0, %1, %2" : "=v"(d1) : "v"(sa[14]), "v"(sa[15]));
      U8 A1, A2;
      A1.u[0] = a0; A1.u[1] = a1; A1.u[2] = b0; A1.u[3] = b1;
      A2.u[0] = c0; A2.u[1] = c1; A2.u[2] = d0; A2.u[3] = d1;

      __builtin_amdgcn_s_setprio(1);
      o[sub] = MFMA32(A1.v, vf0, o[sub]);
      o[sub] = MFMA32(A2.v, vf1, o[sub]);
      __builtin_amdgcn_s_setprio(0);
    }
  }

  // epilogue: shuffle l into the C-layout rows once, divide, store
#pragma unroll
  for (int sub = 0; sub < 2; sub++) {
    float linv = 1.0f / l[sub];
#pragma unroll
    for (int r = 0; r < 16; r++) {
      int q_local = (r & 3) + 8 * (r >> 2) + 4 * hi;
      float lv = __shfl(linv, q_local);
      int qa = w * 64 + sub * 32 + q_local;
      ctx[((size_t)(b << 8) + qa) * 192 + h * 32 + q5] = (bf16)(o[sub][r] * lv);
    }
  }
}

// ---------------------------------------------------------------------------
// Kernel D: out = ctx @ w_proj + b_proj (unchanged).  grid 512, rt=2.
// ---------------------------------------------------------------------------
#define SMEM_C (192 * 200 * 2)

__global__ __launch_bounds__(256) void proj_kernel(
    const bf16* __restrict__ ctx, const bf16* __restrict__ wpT,
    const float* __restrict__ b_proj, float* __restrict__ out) {
  extern __shared__ char smem[];
  bf16* wt = (bf16*)smem;   // [192 c][200 k]
  const int tid = threadIdx.x;
#pragma unroll
  for (int it = 0; it < 18; it++) {
    int idx = it * 256 + tid;
    int c = idx / 24, ch = idx % 24;
    bf16x8 v8 = *(const bf16x8*)(wpT + (size_t)c * 192 + ch * 8);
    *(bf16x8*)(wt + c * 200 + ch * 8) = v8;
  }
  __syncthreads();
  const int lane = tid & 63, w = tid >> 6;
  const int cI = lane & 15, gI = lane >> 4;
  const int row0 = blockIdx.x * 128 + w * 32;
  bf16x8 afr[2][6];
#pragma unroll
  for (int rt = 0; rt < 2; rt++) {
#pragma unroll
    for (int kk = 0; kk < 6; kk++)
      afr[rt][kk] = *(const bf16x8*)(ctx + (size_t)(row0 + rt * 16 + cI) * 192 +
                                     kk * 32 + gI * 8);
  }
#pragma unroll
  for (int ct = 0; ct < 12; ct++) {
    bf16x8 wfr[6];
#pragma unroll
    for (int kk = 0; kk < 6; kk++)
      wfr[kk] = *(const bf16x8*)(wt + (ct * 16 + cI) * 200 + kk * 32 + gI * 8);
    f32x4 bv4 = *(const f32x4*)(b_proj + ct * 16 + gI * 4);
#pragma unroll
    for (int rt = 0; rt < 2; rt++) {
      f32x4 acc = {0.f, 0.f, 0.f, 0.f};
#pragma unroll
      for (int kk = 0; kk < 6; kk++) acc = MFMA(wfr[kk], afr[rt][kk], acc);
      f32x4 res;
#pragma unroll
      for (int r = 0; r < 4; r++) res[r] = acc[r] + bv4[r];
      *(f32x4*)(out + (size_t)(row0 + rt * 16 + cI) * 192 + ct * 16 + gI * 4) = res;
    }
  }
}

// ---------------------------------------------------------------------------
extern "C" void kernel_launch(void* const* d_in, const int* in_sizes, int n_in,
                              void* d_out, int out_size, void* d_ws, size_t ws_size,
                              hipStream_t stream) {
  (void)in_sizes; (void)n_in; (void)out_size; (void)ws_size;
  const float* x      = (const float*)d_in[0];
  const float* mask   = (const float*)d_in[1];
  const float* w_qkv  = (const float*)d_in[2];
  const float* b_qkv  = (const float*)d_in[3];
  const float* w_proj = (const float*)d_in[4];
  const float* b_proj = (const float*)d_in[5];
  const float* pw0    = (const float*)d_in[6];
  const float* pb0    = (const float*)d_in[7];
  const float* g1     = (const float*)d_in[8];
  const float* be1    = (const float*)d_in[9];
  const float* w1     = (const float*)d_in[10];
  const float* b1     = (const float*)d_in[11];
  const float* g2     = (const float*)d_in[12];
  const float* be2    = (const float*)d_in[13];
  const float* w2     = (const float*)d_in[14];
  const float* b2     = (const float*)d_in[15];
  const float* g3     = (const float*)d_in[16];
  const float* be3    = (const float*)d_in[17];
  const float* w3     = (const float*)d_in[18];
  const float* b3     = (const float*)d_in[19];

  // ws layout (peak ~96.5 MB, as R9):
  //   posw   @ 0         (24576)
  //   wqT    @ 24576     (221184)
  //   wpT    @ 245760    (73728)
  //   pos32g @ 319488    (190464)
  //   qw     @ 516096    (25165824)
  //   kw     @ 25681920  (25165824)
  //   vwT    @ 50847744  (25165824)
  //   ctx    @ 76013568  (25165824)
  // maskp (f16 [64][8][8][64][16] = 8,388,608 B) lives in d_out (50 MB);
  // proj_kernel fully overwrites d_out afterwards.
  char* ws = (char*)d_ws;
  float* posw   = (float*)ws;
  bf16*  wqT    = (bf16*)(ws + 24576);
  bf16*  wpT    = (bf16*)(ws + 245760);
  bf16*  pos32g = (bf16*)(ws + 319488);
  bf16*  qw     = (bf16*)(ws + 516096);
  bf16*  kw     = (bf16*)(ws + 25681920);
  bf16*  vwT    = (bf16*)(ws + 50847744);
  bf16*  ctx    = (bf16*)(ws + 76013568);
  _Float16* maskp = (_Float16*)d_out;
  float* outp   = (float*)d_out;

  hipFuncSetAttribute((const void*)qkv_gemm_kernel,
                      hipFuncAttributeMaxDynamicSharedMemorySize, SMEM_G);
  hipFuncSetAttribute((const void*)proj_kernel,
                      hipFuncAttributeMaxDynamicSharedMemorySize, SMEM_C);

  precast_kernel<<<dim3(576), dim3(256), 0, stream>>>(w_qkv, w_proj, wqT, wpT);
  pos_mlp_kernel<<<dim3(4), dim3(256), 0, stream>>>(
      pw0, pb0, g1, be1, w1, b1, g2, be2, w2, b2, g3, be3, w3, b3, posw);
  pos32_build_kernel<<<dim3(31, 6), dim3(256), 0, stream>>>(posw, pos32g);
  maskprep_kernel<<<dim3(8192), dim3(256), 0, stream>>>(mask, maskp);
  qkv_gemm_kernel<<<dim3(512), dim3(256), SMEM_G, stream>>>(
      x, wqT, b_qkv, qw, kw, vwT);
  attn_kernel<<<dim3(1536), dim3(256), 0, stream>>>(
      qw, kw, vwT, maskp, pos32g, ctx);
  proj_kernel<<<dim3(512), dim3(256), SMEM_C, stream>>>(
      ctx, wpT, b_proj, outp);
}